// Round 1
// baseline (80.411 us; speedup 1.0000x reference)
//
#include <hip/hip_runtime.h>

#define B_ 4
#define C_ 64
#define N_ 512
#define H_ 128   // hidden width = 2C

// ---------------------------------------------------------------------------
// Kernel 1: factorized first-layer projections.
//   L[b,i,h] = sum_c x[b,c,i] * W1[c,h]
//   R[b,j,h] = sum_c x[b,c,j] * W1[64+c,h] + b1[h]   (b1 folded into R)
// Output layout: [b][row][h], h contiguous (stride H_).
// Grid: 256 blocks = 2 halves x 4 b x 32 i-tiles(16 rows). Block 256 threads.
// ---------------------------------------------------------------------------
__global__ __launch_bounds__(256) void proj_kernel(
    const float* __restrict__ x, const float* __restrict__ W1,
    const float* __restrict__ b1, float* __restrict__ Lbuf,
    float* __restrict__ Rbuf)
{
    __shared__ float Wl[64 * 128];   // 32 KB: one half of W1 (64 rows x 128 cols)
    __shared__ float xs[16 * 68];    // x tile, transposed [ii][c], padded stride 68

    const int t    = threadIdx.x;
    const int half = blockIdx.x >> 7;          // 0 = L, 1 = R
    const int rem  = blockIdx.x & 127;
    const int b    = rem >> 5;
    const int i0   = (rem & 31) * 16;
    const int cbase = half * 64;

    // stage W half: rows cbase..cbase+63, all 128 cols = 2048 float4, coalesced
    const float4* W14 = (const float4*)W1;
    float4* Wl4 = (float4*)Wl;
    #pragma unroll
    for (int k = 0; k < 8; ++k)
        Wl4[t + k * 256] = W14[cbase * 32 + t + k * 256];

    // stage x tile: xs[ii*68 + c] = x[b, c, i0+ii]
    #pragma unroll
    for (int k = 0; k < 4; ++k) {
        int idx = t + k * 256;                  // 0..1023
        int c = idx >> 4, ii = idx & 15;
        xs[ii * 68 + c] = x[b * (C_ * N_) + c * N_ + i0 + ii];
    }
    __syncthreads();

    const int hq  = t & 31;           // column quad (4 h's)
    const int il  = (t >> 5) * 2;     // local row base (2 rows per thread)
    const int col = hq * 4;

    float4 a0, a1;
    if (half) { a0 = *(const float4*)(b1 + col); a1 = a0; }
    else      { a0 = make_float4(0.f, 0.f, 0.f, 0.f); a1 = a0; }

    #pragma unroll
    for (int c = 0; c < 64; c += 4) {
        float4 xv0 = *(float4*)(xs + il * 68 + c);
        float4 xv1 = *(float4*)(xs + (il + 1) * 68 + c);
        const float* x0p = (const float*)&xv0;
        const float* x1p = (const float*)&xv1;
        #pragma unroll
        for (int cc = 0; cc < 4; ++cc) {
            float4 w = Wl4[(c + cc) * 32 + hq];
            a0.x = fmaf(w.x, x0p[cc], a0.x);
            a0.y = fmaf(w.y, x0p[cc], a0.y);
            a0.z = fmaf(w.z, x0p[cc], a0.z);
            a0.w = fmaf(w.w, x0p[cc], a0.w);
            a1.x = fmaf(w.x, x1p[cc], a1.x);
            a1.y = fmaf(w.y, x1p[cc], a1.y);
            a1.z = fmaf(w.z, x1p[cc], a1.z);
            a1.w = fmaf(w.w, x1p[cc], a1.w);
        }
    }

    float* buf = half ? Rbuf : Lbuf;
    float* o = buf + b * (N_ * H_) + (i0 + il) * H_ + col;
    *(float4*)o = a0;
    *(float4*)(o + H_) = a1;
}

// ---------------------------------------------------------------------------
// Kernel 2: pairwise scores.
//   out[b,i,j] = (j > i) ? sum_h relu(L[i,h] + R[j,h]) * W2[h] + b2 : 0
// Block = 64x64 tile for one b (grid 4 x 8 x 8 = 256). 256 threads:
// 4 waves of 32x32, thread tile 4x4, h vectorized by float4.
// LDS: Lt/Rt 64x128 floats each (64 KB total) with quad-rotation swizzle
//   col_quad' = (hc + row/4) & 31  -> conflict-free compute-phase reads.
// ---------------------------------------------------------------------------
__global__ __launch_bounds__(256) void pair_kernel(
    const float* __restrict__ Lbuf, const float* __restrict__ Rbuf,
    const float* __restrict__ W2, const float* __restrict__ b2,
    float* __restrict__ out)
{
    __shared__ float Lt[64 * 128];   // 32 KB
    __shared__ float Rt[64 * 128];   // 32 KB

    const int t    = threadIdx.x;
    const int b    = blockIdx.x >> 6;
    const int tile = blockIdx.x & 63;
    const int ti0  = (tile >> 3) * 64;
    const int tj0  = (tile & 7) * 64;

    float* outb = out + b * (N_ * N_);

    if (tj0 < ti0) {
        // tile entirely in strict lower triangle (j <= i everywhere): zeros
        float4 z = make_float4(0.f, 0.f, 0.f, 0.f);
        #pragma unroll
        for (int k = 0; k < 4; ++k) {
            int idx4 = t + k * 256;            // 0..1023
            int r = idx4 >> 4, cc = idx4 & 15;
            *(float4*)(outb + (ti0 + r) * N_ + tj0 + cc * 4) = z;
        }
        return;
    }

    // stage L and R tiles (2048 float4 each), swizzled
    float4* Lt4 = (float4*)Lt;
    float4* Rt4 = (float4*)Rt;
    #pragma unroll
    for (int k = 0; k < 8; ++k) {
        int idx4 = t + k * 256;                // 0..2047
        int row = idx4 >> 5, hc = idx4 & 31;
        float4 lv = *(const float4*)(Lbuf + b * (N_ * H_) + (ti0 + row) * H_ + hc * 4);
        float4 rv = *(const float4*)(Rbuf + b * (N_ * H_) + (tj0 + row) * H_ + hc * 4);
        int sc = (hc + (row >> 2)) & 31;       // swizzled col quad
        Lt4[row * 32 + sc] = lv;
        Rt4[row * 32 + sc] = rv;
    }
    __syncthreads();

    const int w    = t >> 6;
    const int lane = t & 63;
    const int wi   = (w >> 1) * 32, wj = (w & 1) * 32;
    const int til  = wi + ((lane >> 3) & 7) * 4;   // local i base (4 rows)
    const int tjl  = wj + (lane & 7) * 4;          // local j base (4 cols)
    const int rotL = til >> 2;                     // constant per thread
    const int rotR = tjl >> 2;

    float acc[4][4];
    #pragma unroll
    for (int r = 0; r < 4; ++r)
        #pragma unroll
        for (int c = 0; c < 4; ++c) acc[r][c] = 0.f;

    #pragma unroll 2
    for (int hc = 0; hc < 32; ++hc) {
        const int scL = (hc + rotL) & 31;
        const int scR = (hc + rotR) & 31;
        float4 Lr[4], Rc[4];
        #pragma unroll
        for (int r = 0; r < 4; ++r) Lr[r] = Lt4[(til + r) * 32 + scL];
        #pragma unroll
        for (int c = 0; c < 4; ++c) Rc[c] = Rt4[(tjl + c) * 32 + scR];
        float4 wv = *(const float4*)(W2 + hc * 4);   // uniform -> s_load
        const float* wp = (const float*)&wv;
        #pragma unroll
        for (int r = 0; r < 4; ++r) {
            const float* lp = (const float*)&Lr[r];
            #pragma unroll
            for (int c = 0; c < 4; ++c) {
                const float* rp = (const float*)&Rc[c];
                float s = acc[r][c];
                #pragma unroll
                for (int k = 0; k < 4; ++k) {
                    float v = fmaxf(lp[k] + rp[k], 0.f);
                    s = fmaf(v, wp[k], s);
                }
                acc[r][c] = s;
            }
        }
    }

    const float bias2 = b2[0];
    #pragma unroll
    for (int r = 0; r < 4; ++r) {
        const int gi = ti0 + til + r;
        float4 v;
        float* vp = (float*)&v;
        #pragma unroll
        for (int c = 0; c < 4; ++c) {
            const int gj = tj0 + tjl + c;
            vp[c] = (gj > gi) ? (acc[r][c] + bias2) : 0.f;
        }
        *(float4*)(outb + gi * N_ + tj0 + tjl) = v;
    }
}

extern "C" void kernel_launch(void* const* d_in, const int* in_sizes, int n_in,
                              void* d_out, int out_size, void* d_ws, size_t ws_size,
                              hipStream_t stream)
{
    const float* x  = (const float*)d_in[0];
    const float* W1 = (const float*)d_in[1];
    const float* b1 = (const float*)d_in[2];
    const float* W2 = (const float*)d_in[3];
    const float* b2 = (const float*)d_in[4];
    float* out  = (float*)d_out;
    float* Lbuf = (float*)d_ws;                 // B*N*H floats = 1 MB
    float* Rbuf = Lbuf + B_ * N_ * H_;          // +1 MB

    proj_kernel<<<256, 256, 0, stream>>>(x, W1, b1, Lbuf, Rbuf);
    pair_kernel<<<B_ * 64, 256, 0, stream>>>(Lbuf, Rbuf, W2, b2, out);
}

// Round 2
// 77.683 us; speedup vs baseline: 1.0351x; 1.0351x over previous
//
#include <hip/hip_runtime.h>

#define B_ 4
#define C_ 64
#define N_ 512
#define H_ 128   // hidden width = 2C

// ---------------------------------------------------------------------------
// Kernel 1: factorized first-layer projections.
//   L[b,i,h] = sum_c x[b,c,i] * W1[c,h]
//   R[b,j,h] = sum_c x[b,c,j] * W1[64+c,h] + b1[h]   (b1 folded into R)
// Output layout: [b][row][h], h contiguous (stride H_).
// Grid: 256 blocks = 2 halves x 4 b x 32 i-tiles(16 rows). Block 256 threads.
// ---------------------------------------------------------------------------
__global__ __launch_bounds__(256) void proj_kernel(
    const float* __restrict__ x, const float* __restrict__ W1,
    const float* __restrict__ b1, float* __restrict__ Lbuf,
    float* __restrict__ Rbuf)
{
    __shared__ float Wl[64 * 128];   // 32 KB: one half of W1 (64 rows x 128 cols)
    __shared__ float xs[16 * 68];    // x tile, transposed [ii][c], padded stride 68

    const int t    = threadIdx.x;
    const int half = blockIdx.x >> 7;          // 0 = L, 1 = R
    const int rem  = blockIdx.x & 127;
    const int b    = rem >> 5;
    const int i0   = (rem & 31) * 16;
    const int cbase = half * 64;

    // stage W half: rows cbase..cbase+63, all 128 cols = 2048 float4, coalesced
    const float4* W14 = (const float4*)W1;
    float4* Wl4 = (float4*)Wl;
    #pragma unroll
    for (int k = 0; k < 8; ++k)
        Wl4[t + k * 256] = W14[cbase * 32 + t + k * 256];

    // stage x tile: xs[ii*68 + c] = x[b, c, i0+ii]
    #pragma unroll
    for (int k = 0; k < 4; ++k) {
        int idx = t + k * 256;                  // 0..1023
        int c = idx >> 4, ii = idx & 15;
        xs[ii * 68 + c] = x[b * (C_ * N_) + c * N_ + i0 + ii];
    }
    __syncthreads();

    const int hq  = t & 31;           // column quad (4 h's)
    const int il  = (t >> 5) * 2;     // local row base (2 rows per thread)
    const int col = hq * 4;

    float4 a0, a1;
    if (half) { a0 = *(const float4*)(b1 + col); a1 = a0; }
    else      { a0 = make_float4(0.f, 0.f, 0.f, 0.f); a1 = a0; }

    #pragma unroll
    for (int c = 0; c < 64; c += 4) {
        float4 xv0 = *(float4*)(xs + il * 68 + c);
        float4 xv1 = *(float4*)(xs + (il + 1) * 68 + c);
        const float* x0p = (const float*)&xv0;
        const float* x1p = (const float*)&xv1;
        #pragma unroll
        for (int cc = 0; cc < 4; ++cc) {
            float4 w = Wl4[(c + cc) * 32 + hq];
            a0.x = fmaf(w.x, x0p[cc], a0.x);
            a0.y = fmaf(w.y, x0p[cc], a0.y);
            a0.z = fmaf(w.z, x0p[cc], a0.z);
            a0.w = fmaf(w.w, x0p[cc], a0.w);
            a1.x = fmaf(w.x, x1p[cc], a1.x);
            a1.y = fmaf(w.y, x1p[cc], a1.y);
            a1.z = fmaf(w.z, x1p[cc], a1.z);
            a1.w = fmaf(w.w, x1p[cc], a1.w);
        }
    }

    float* buf = half ? Rbuf : Lbuf;
    float* o = buf + b * (N_ * H_) + (i0 + il) * H_ + col;
    *(float4*)o = a0;
    *(float4*)(o + H_) = a1;
}

// ---------------------------------------------------------------------------
// Kernel 2: pairwise scores, 32x32 tiles for load balance + occupancy.
//   out[b,i,j] = (j > i) ? sum_h relu(L[i,h] + R[j,h]) * W2[h] + b2 : 0
// Grid: 4 b x 256 tiles (16x16 of 32x32) = 1024 blocks, 256 threads.
// Strictly-lower tiles: fast zero-fill (1 float4/thread). Work tiles:
// LDS 2 x 32row x 32quad float4 (32 KB total -> 4 blocks/CU), 4 waves of
// 16x16, thread tile 2x2 over h in float4 chunks.
// Swizzle col_quad' = (hc + row/4) & 31: a wave's 8 distinct rows land on
// 16 banks x 2-way (free per m136).
// ---------------------------------------------------------------------------
__global__ __launch_bounds__(256) void pair_kernel(
    const float* __restrict__ Lbuf, const float* __restrict__ Rbuf,
    const float* __restrict__ W2, const float* __restrict__ b2,
    float* __restrict__ out)
{
    __shared__ float4 Lt4[32 * 32];   // 16 KB
    __shared__ float4 Rt4[32 * 32];   // 16 KB

    const int t    = threadIdx.x;
    const int b    = blockIdx.x >> 8;
    const int tile = blockIdx.x & 255;
    const int ti0  = (tile >> 4) * 32;
    const int tj0  = (tile & 15) * 32;

    float* outb = out + b * (N_ * N_);

    if (tj0 + 31 <= ti0) {
        // tile entirely in strict lower triangle (j <= i everywhere): zeros
        const int r = t >> 3, cq = t & 7;      // 32 rows x 8 float4-cols
        *(float4*)(outb + (ti0 + r) * N_ + tj0 + cq * 4) =
            make_float4(0.f, 0.f, 0.f, 0.f);
        return;
    }

    // stage L and R tiles: 1024 float4 each, 4 per thread per tile
    const float* Lsrc = Lbuf + b * (N_ * H_) + ti0 * H_;
    const float* Rsrc = Rbuf + b * (N_ * H_) + tj0 * H_;
    #pragma unroll
    for (int k = 0; k < 4; ++k) {
        int idx = t + k * 256;                 // 0..1023
        int row = idx >> 5, hc = idx & 31;
        int sc = (hc + (row >> 2)) & 31;
        Lt4[row * 32 + sc] = *(const float4*)(Lsrc + row * H_ + hc * 4);
        Rt4[row * 32 + sc] = *(const float4*)(Rsrc + row * H_ + hc * 4);
    }
    __syncthreads();

    const int w    = t >> 6;
    const int lane = t & 63;
    const int til  = (w >> 1) * 16 + (lane >> 3) * 2;  // local i base (2 rows)
    const int tjl  = (w & 1) * 16 + (lane & 7) * 2;    // local j base (2 cols)
    const int rotL = til >> 2;                         // (til+1)>>2 == til>>2 (til even)
    const int rotR = tjl >> 2;

    float a00 = 0.f, a01 = 0.f, a10 = 0.f, a11 = 0.f;
    const float4* W24 = (const float4*)W2;

    #pragma unroll 4
    for (int hc = 0; hc < 32; ++hc) {
        float4 L0 = Lt4[til * 32 + ((hc + rotL) & 31)];
        float4 L1 = Lt4[(til + 1) * 32 + ((hc + rotL) & 31)];
        float4 R0 = Rt4[tjl * 32 + ((hc + rotR) & 31)];
        float4 R1 = Rt4[(tjl + 1) * 32 + ((hc + rotR) & 31)];
        float4 wv = W24[hc];                   // wave-uniform -> scalar load
        const float* l0 = (const float*)&L0;
        const float* l1 = (const float*)&L1;
        const float* r0 = (const float*)&R0;
        const float* r1 = (const float*)&R1;
        const float* wp = (const float*)&wv;
        #pragma unroll
        for (int k = 0; k < 4; ++k) {
            a00 = fmaf(fmaxf(l0[k] + r0[k], 0.f), wp[k], a00);
            a01 = fmaf(fmaxf(l0[k] + r1[k], 0.f), wp[k], a01);
            a10 = fmaf(fmaxf(l1[k] + r0[k], 0.f), wp[k], a10);
            a11 = fmaf(fmaxf(l1[k] + r1[k], 0.f), wp[k], a11);
        }
    }

    const float bias2 = b2[0];
    const int gi0 = ti0 + til, gj0 = tj0 + tjl;
    float2 v0, v1;
    v0.x = (gj0     > gi0    ) ? (a00 + bias2) : 0.f;
    v0.y = (gj0 + 1 > gi0    ) ? (a01 + bias2) : 0.f;
    v1.x = (gj0     > gi0 + 1) ? (a10 + bias2) : 0.f;
    v1.y = (gj0 + 1 > gi0 + 1) ? (a11 + bias2) : 0.f;
    *(float2*)(outb + gi0 * N_ + gj0) = v0;
    *(float2*)(outb + (gi0 + 1) * N_ + gj0) = v1;
}

extern "C" void kernel_launch(void* const* d_in, const int* in_sizes, int n_in,
                              void* d_out, int out_size, void* d_ws, size_t ws_size,
                              hipStream_t stream)
{
    const float* x  = (const float*)d_in[0];
    const float* W1 = (const float*)d_in[1];
    const float* b1 = (const float*)d_in[2];
    const float* W2 = (const float*)d_in[3];
    const float* b2 = (const float*)d_in[4];
    float* out  = (float*)d_out;
    float* Lbuf = (float*)d_ws;                 // B*N*H floats = 1 MB
    float* Rbuf = Lbuf + B_ * N_ * H_;          // +1 MB

    proj_kernel<<<256, 256, 0, stream>>>(x, W1, b1, Lbuf, Rbuf);
    pair_kernel<<<B_ * 256, 256, 0, stream>>>(Lbuf, Rbuf, W2, b2, out);
}